// Round 11
// baseline (74.528 us; speedup 1.0000x reference)
//
#include <hip/hip_runtime.h>
#include <math.h>

#define BLOCK 256

// ---------- compile-time machinery ----------
template <int I> struct IC { static constexpr int value = I; };

template <int I, int N, typename F>
__device__ __forceinline__ void static_for(F&& f) {
  if constexpr (I < N) {
    f(IC<I>{});
    static_for<I + 1, N>(f);
  }
}

// corner index bits: bit2 -> x sign, bit1 -> y sign, bit0 -> z sign.
constexpr int permute_bits(int k, int p) {
  int b2 = (k >> 2) & 1, b1 = (k >> 1) & 1, b0 = k & 1;
  switch (p) {
    case 0: return (b2 << 2) | (b1 << 1) | b0;
    case 1: return (b2 << 2) | (b0 << 1) | b1;
    case 2: return (b1 << 2) | (b2 << 1) | b0;
    case 3: return (b1 << 2) | (b0 << 1) | b2;
    case 4: return (b0 << 2) | (b2 << 1) | b1;
    default: return (b0 << 2) | (b1 << 1) | b2;
  }
}

// Abramowitz-Stegun 4.4.45: acos(x) for x in [0,1], |err| <= 6.7e-5 rad.
__device__ __forceinline__ float acos_fast(float x) {
  float r = sqrtf(fmaxf(1.0f - x, 0.0f));
  float p = fmaf(x, -0.0187293f, 0.0742610f);
  p = fmaf(x, p, -0.2121144f);
  p = fmaf(x, p, 1.5707288f);
  return r * p;
}

__device__ __forceinline__ void quat_mat(float x, float y, float z, float w,
                                         float eps, float R[9]) {
  float n = sqrtf(x * x + y * y + z * z + w * w);
  float s = 1.0f / (n + eps);
  x *= s; y *= s; z *= s; w *= s;
  R[0] = 1.0f - 2.0f * y * y - 2.0f * z * z;
  R[1] = 2.0f * x * y - 2.0f * z * w;
  R[2] = 2.0f * x * z + 2.0f * y * w;
  R[3] = 2.0f * x * y + 2.0f * z * w;
  R[4] = 1.0f - 2.0f * x * x - 2.0f * z * z;
  R[5] = 2.0f * y * z - 2.0f * x * w;
  R[6] = 2.0f * x * z - 2.0f * y * w;
  R[7] = 2.0f * y * z + 2.0f * x * w;
  R[8] = 1.0f - 2.0f * x * x - 2.0f * y * y;
}

__device__ __forceinline__ float sel3(float v0, float v1, float v2, int i) {
  return i == 0 ? v0 : (i == 1 ? v1 : v2);
}
__device__ __forceinline__ int sel3i(int v0, int v1, int v2, int i) {
  return i == 0 ? v0 : (i == 1 ? v1 : v2);
}

// Block of 256 = 4 waves handles 128 boxes: waves 0-1 = role A (scalar
// losses + IoU) for boxes 0-127; waves 2-3 = role B (corners + assignment)
// for the SAME boxes. Role branch is wave-uniform -> no divergence cost.
// Rationale: grid-limited occupancy (2048 waves = 2/SIMD) was the binder;
// this doubles waves while duplicating only loads + quat matrices.
__global__ __launch_bounds__(BLOCK)
void hybrid_loss_kernel(const float* __restrict__ pred,
                        const float* __restrict__ gt,
                        float* __restrict__ out, int B, float invB) {
  int lane = threadIdx.x & 63;
  int wid = threadIdx.x >> 6;   // 0..3
  int role = wid >> 1;          // 0: scalar+iou, 1: corners+assignment
  int b = blockIdx.x * 128 + (wid & 1) * 64 + lane;
  float contrib = 0.0f;

  if (b < B) {
    // ---- shared front matter (both roles) ----
    const float2* p2 = reinterpret_cast<const float2*>(pred) + (size_t)b * 5;
    const float2* g2 = reinterpret_cast<const float2*>(gt) + (size_t)b * 5;
    float2 pA = p2[0], pB = p2[1], pC = p2[2], pD = p2[3], pE = p2[4];
    float2 gA = g2[0], gB = g2[1], gC = g2[2], gD = g2[3], gE = g2[4];
    float px = pA.x, py = pA.y, pz = pB.x;
    float pdx = pB.y, pdy = pC.x, pdz = pC.y;
    float pqx = pD.x, pqy = pD.y, pqz = pE.x, pqw = pE.y;
    float gx = gA.x, gy = gA.y, gz = gB.x;
    float gdx = gB.y, gdy = gC.x, gdz = gC.y;
    float gqx = gD.x, gqy = gD.y, gqz = gE.x, gqw = gE.y;

    float gdiag = sqrtf(gdx * gdx + gdy * gdy + gdz * gdz);

    float Rp[9], Rg[9];
    quat_mat(pqx, pqy, pqz, pqw, 1e-8f, Rp);
    quat_mat(gqx, gqy, gqz, gqw, 1e-8f, Rg);

    float phx = 0.5f * pdx, phy = 0.5f * pdy, phz = 0.5f * pdz;
    float ghx = 0.5f * gdx, ghy = 0.5f * gdy, ghz = 0.5f * gdz;
    float pA0x = Rp[0] * phx, pA0y = Rp[3] * phx, pA0z = Rp[6] * phx;
    float pA1x = Rp[1] * phy, pA1y = Rp[4] * phy, pA1z = Rp[7] * phy;
    float pA2x = Rp[2] * phz, pA2y = Rp[5] * phz, pA2z = Rp[8] * phz;
    float gA0x = Rg[0] * ghx, gA0y = Rg[3] * ghx, gA0z = Rg[6] * ghx;
    float gA1x = Rg[1] * ghy, gA1y = Rg[4] * ghy, gA1z = Rg[7] * ghy;
    float gA2x = Rg[2] * ghz, gA2y = Rg[5] * ghz, gA2z = Rg[8] * ghz;

    if (role == 0) {
      // ================= role A: scalar losses + projected IoU ===========
      float s_diag = fabsf(pdx - gdx) / (gdx + 1e-6f)
                   + fabsf(pdy - gdy) / (gdy + 1e-6f)
                   + fabsf(pdz - gdz) / (gdz + 1e-6f);
      float s_center =
          (fabsf(px - gx) + fabsf(py - gy) + fabsf(pz - gz)) / gdiag;

      float s_quat = 0.0f;
#pragma unroll
      for (int i = 0; i < 3; ++i) {
        float m = 0.0f;
#pragma unroll
        for (int j = 0; j < 3; ++j) {
          float d = fabsf(Rp[i] * Rg[j] + Rp[3 + i] * Rg[3 + j] +
                          Rp[6 + i] * Rg[6 + j]);
          m = fmaxf(m, d);
        }
        m = fminf(fmaxf(m, 1e-6f), 1.0f);
        s_quat += acos_fast(m);
      }

      int q0 = 0, q1 = 1, q2 = 2;
      float v0 = pdx, v1 = pdy, v2 = pdz;
      if (v1 > v0) { float t = v0; v0 = v1; v1 = t; int ti = q0; q0 = q1; q1 = ti; }
      if (v2 > v1) { float t = v1; v1 = v2; v2 = t; int ti = q1; q1 = q2; q2 = ti; }
      if (v1 > v0) { float t = v0; v0 = v1; v1 = t; int ti = q0; q0 = q1; q1 = ti; }
      int r0 = 0, r1 = 1, r2 = 2;
      float u0 = gdx, u1 = gdy, u2 = gdz;
      if (u1 > u0) { float t = u0; u0 = u1; u1 = t; int ti = r0; r0 = r1; r1 = ti; }
      if (u2 > u1) { float t = u1; u1 = u2; u2 = t; int ti = r1; r1 = r2; r2 = ti; }
      if (u1 > u0) { float t = u0; u0 = u1; u1 = t; int ti = r0; r0 = r1; r1 = ti; }

      float s_cdims = fabsf(v0 - u0) / (u0 + 1e-8f)
                    + fabsf(v1 - u1) / (u1 + 1e-8f)
                    + fabsf(v2 - u2) / (u2 + 1e-8f);

      int ig0 = (r0 == 0) ? 0 : ((r1 == 0) ? 1 : 2);
      int ig1 = (r0 == 1) ? 0 : ((r1 == 1) ? 1 : 2);
      int ig2 = (r0 == 2) ? 0 : ((r1 == 2) ? 1 : 2);
      int t0 = sel3i(ig0, ig1, ig2, q0);
      int t1 = sel3i(ig0, ig1, ig2, q1);
      int t2 = sel3i(ig0, ig1, ig2, q2);

      float s_cang = 0.0f;
#pragma unroll
      for (int i = 0; i < 3; ++i) {
        float gg0 = Rg[i * 3 + 0], gg1 = Rg[i * 3 + 1], gg2 = Rg[i * 3 + 2];
        float ds = Rp[i * 3 + 0] * sel3(gg0, gg1, gg2, t0)
                 + Rp[i * 3 + 1] * sel3(gg0, gg1, gg2, t1)
                 + Rp[i * 3 + 2] * sel3(gg0, gg1, gg2, t2);
        float ad = fminf(fabsf(ds), 1.0f);
        s_cang += acos_fast(ad);
      }

      // closed-form OBB axis extents (== corner min/max, no corner loop)
      float pex = fabsf(pA0x) + fabsf(pA1x) + fabsf(pA2x);
      float pey = fabsf(pA0y) + fabsf(pA1y) + fabsf(pA2y);
      float pez = fabsf(pA0z) + fabsf(pA1z) + fabsf(pA2z);
      float gex = fabsf(gA0x) + fabsf(gA1x) + fabsf(gA2x);
      float gey = fabsf(gA0y) + fabsf(gA1y) + fabsf(gA2y);
      float gez = fabsf(gA0z) + fabsf(gA1z) + fabsf(gA2z);
      float pmnx = px - pex, pmxx = px + pex;
      float pmny = py - pey, pmxy = py + pey;
      float pmnz = pz - pez, pmxz = pz + pez;
      float gmnx = gx - gex, gmxx = gx + gex;
      float gmny = gy - gey, gmxy = gy + gey;
      float gmnz = gz - gez, gmxz = gz + gez;

      auto plane_iou = [&](float a1n, float a1x, float b1n, float b1x,
                           float a2n, float a2x, float b2n, float b2x,
                           float p1n, float p1x, float p2n,
                           float p2x) -> float {
        const float eps = 1e-3f;
        float ia = fmaxf(fminf(a1x, a2x) - fmaxf(a1n, a2n) + eps, 0.0f);
        float ib = fmaxf(fminf(b1x, b2x) - fmaxf(b1n, b2n) + eps, 0.0f);
        float inter = ia * ib;
        float ar1 = (a1x - a1n + eps) * (b1x - b1n + eps);
        float ar2 = (a2x - a2n + eps) * (b2x - b2n + eps);
        float iou2d = inter / (ar1 + ar2 - inter + 1e-6f);
        float hi = fmaxf(fminf(p1x, p2x) - fmaxf(p1n, p2n), 0.0f);
        float hu = (p1x - p1n) + (p2x - p2n) - hi;
        return iou2d * (hi / (hu + 1e-6f));
      };
      float iou_sum = 0.0f;
      iou_sum += plane_iou(pmnx, pmxx, pmnz, pmxz, gmnx, gmxx, gmnz, gmxz,
                           pmny, pmxy, gmny, gmxy);
      iou_sum += plane_iou(pmnx, pmxx, pmny, pmxy, gmnx, gmxx, gmny, gmxy,
                           pmnz, pmxz, gmnz, gmxz);
      iou_sum += plane_iou(pmny, pmxy, pmnz, pmxz, gmny, gmxy, gmnz, gmxz,
                           pmnx, pmxx, gmnx, gmxx);
      float iou_b = fminf(fmaxf(iou_sum * (1.0f / 3.0f), 0.0f), 1.0f);

      const float third = (1.0f / 3.0f);
      float loss_a = 0.15f * s_diag * third
                   + 0.2f * s_center * third
                   + 0.15f * s_quat * third
                   + 0.1f * (0.5f * s_cdims * third + 0.5f * s_cang * third)
                   - 0.2f * iou_b;
      contrib = loss_a * invB;
      if (b == 0) contrib += 0.2f;  // W['iou'] * 1.0 constant term
    } else {
      // ============ role B: corners + 48-perm corner assignment ==========
      float corner_scale = 0.2f * 0.125f / (gdiag + 1e-6f);

      float pcx[8], pcy[8], pcz[8], gcx[8], gcy[8], gcz[8];
#pragma unroll
      for (int k = 0; k < 8; ++k) {
        float sx = (k & 4) ? -1.0f : 1.0f;
        float sy = (k & 2) ? -1.0f : 1.0f;
        float sz = (k & 1) ? -1.0f : 1.0f;
        pcx[k] = px + sx * pA0x + sy * pA1x + sz * pA2x;
        pcy[k] = py + sx * pA0y + sy * pA1y + sz * pA2y;
        pcz[k] = pz + sx * pA0z + sy * pA1z + sz * pA2z;
        gcx[k] = gx + sx * gA0x + sy * gA1x + sz * gA2x;
        gcy[k] = gy + sx * gA0y + sy * gA1y + sz * gA2y;
        gcz[k] = gz + sx * gA0z + sy * gA1z + sz * gA2z;
      }

      float D[8][8];
#pragma unroll
      for (int r = 0; r < 8; ++r)
#pragma unroll
        for (int j = 0; j < 8; ++j)
          D[r][j] = fabsf(pcx[r] - gcx[j]) + fabsf(pcy[r] - gcy[j]) +
                    fabsf(pcz[r] - gcz[j]);

      float best = 3.0e38f;
      static_for<0, 48>([&](auto A) {
        constexpr int p = decltype(A)::value / 8;
        constexpr int m = decltype(A)::value & 7;
        float sum = D[0][permute_bits(0, p) ^ m];
        static_for<1, 8>([&](auto K) {
          constexpr int k = decltype(K)::value;
          sum += D[k][permute_bits(k, p) ^ m];
        });
        best = fminf(best, sum);
      });

      contrib = best * corner_scale * invB;
    }
  }

  // ---- reduction: wave shfl -> LDS -> one atomicAdd per block ----
  float s = contrib;
#pragma unroll
  for (int off = 32; off > 0; off >>= 1) s += __shfl_down(s, off, 64);
  __shared__ float red[BLOCK / 64];
  int rlane = threadIdx.x & 63;
  int rwid = threadIdx.x >> 6;
  if (rlane == 0) red[rwid] = s;
  __syncthreads();
  if (threadIdx.x == 0) {
    float tot = red[0] + red[1] + red[2] + red[3];
    atomicAdd(out, tot);
  }
}

extern "C" void kernel_launch(void* const* d_in, const int* in_sizes, int n_in,
                              void* d_out, int out_size, void* d_ws, size_t ws_size,
                              hipStream_t stream) {
  const float* pred = (const float*)d_in[0];
  const float* gt = (const float*)d_in[1];
  float* out = (float*)d_out;
  int B = in_sizes[0] / 10;
  hipMemsetAsync(out, 0, sizeof(float), stream);
  int grid = (B + 127) / 128;  // 128 boxes per 256-thread block (2 roles)
  hybrid_loss_kernel<<<grid, BLOCK, 0, stream>>>(pred, gt, out, B,
                                                 1.0f / (float)B);
}

// Round 12
// 67.136 us; speedup vs baseline: 1.1101x; 1.1101x over previous
//
#include <hip/hip_runtime.h>
#include <math.h>

#define BLOCK 256

// ---------- compile-time machinery ----------
template <int I> struct IC { static constexpr int value = I; };

template <int I, int N, typename F>
__device__ __forceinline__ void static_for(F&& f) {
  if constexpr (I < N) {
    f(IC<I>{});
    static_for<I + 1, N>(f);
  }
}

// corner index bits: bit2 -> x sign, bit1 -> y sign, bit0 -> z sign.
constexpr int permute_bits(int k, int p) {
  int b2 = (k >> 2) & 1, b1 = (k >> 1) & 1, b0 = k & 1;
  switch (p) {
    case 0: return (b2 << 2) | (b1 << 1) | b0;
    case 1: return (b2 << 2) | (b0 << 1) | b1;
    case 2: return (b1 << 2) | (b2 << 1) | b0;
    case 3: return (b1 << 2) | (b0 << 1) | b2;
    case 4: return (b0 << 2) | (b2 << 1) | b1;
    default: return (b0 << 2) | (b1 << 1) | b2;
  }
}

// Abramowitz-Stegun 4.4.45: acos(x) for x in [0,1], |err| <= 6.7e-5 rad.
__device__ __forceinline__ float acos_fast(float x) {
  float r = sqrtf(fmaxf(1.0f - x, 0.0f));
  float p = fmaf(x, -0.0187293f, 0.0742610f);
  p = fmaf(x, p, -0.2121144f);
  p = fmaf(x, p, 1.5707288f);
  return r * p;
}

__device__ __forceinline__ void quat_mat(float x, float y, float z, float w,
                                         float eps, float R[9]) {
  float n = sqrtf(x * x + y * y + z * z + w * w);
  float s = 1.0f / (n + eps);
  x *= s; y *= s; z *= s; w *= s;
  R[0] = 1.0f - 2.0f * y * y - 2.0f * z * z;
  R[1] = 2.0f * x * y - 2.0f * z * w;
  R[2] = 2.0f * x * z + 2.0f * y * w;
  R[3] = 2.0f * x * y + 2.0f * z * w;
  R[4] = 1.0f - 2.0f * x * x - 2.0f * z * z;
  R[5] = 2.0f * y * z - 2.0f * x * w;
  R[6] = 2.0f * x * z - 2.0f * y * w;
  R[7] = 2.0f * y * z + 2.0f * x * w;
  R[8] = 1.0f - 2.0f * x * x - 2.0f * y * y;
}

__device__ __forceinline__ float sel3(float v0, float v1, float v2, int i) {
  return i == 0 ? v0 : (i == 1 ? v1 : v2);
}
__device__ __forceinline__ int sel3i(int v0, int v1, int v2, int i) {
  return i == 0 ? v0 : (i == 1 ? v1 : v2);
}

// Stage 1: per-box loss, block partial -> d_ws[blockIdx]. No atomics
// (512 same-address atomics cost ~5-8 us serialized at the coherence
// point; r11's +512 blocks -> +4.6 us is the fingerprint).
__global__ __launch_bounds__(BLOCK)
void hybrid_loss_kernel(const float* __restrict__ pred,
                        const float* __restrict__ gt,
                        float* __restrict__ partials, int B, float invB) {
  int b = blockIdx.x * BLOCK + threadIdx.x;
  float contrib = 0.0f;
  if (b < B) {
    // ---- load (rows are 40B, 8-byte aligned -> five float2 loads each) ----
    const float2* p2 = reinterpret_cast<const float2*>(pred) + (size_t)b * 5;
    const float2* g2 = reinterpret_cast<const float2*>(gt) + (size_t)b * 5;
    float2 pA = p2[0], pB = p2[1], pC = p2[2], pD = p2[3], pE = p2[4];
    float2 gA = g2[0], gB = g2[1], gC = g2[2], gD = g2[3], gE = g2[4];
    float px = pA.x, py = pA.y, pz = pB.x;
    float pdx = pB.y, pdy = pC.x, pdz = pC.y;
    float pqx = pD.x, pqy = pD.y, pqz = pE.x, pqw = pE.y;
    float gx = gA.x, gy = gA.y, gz = gB.x;
    float gdx = gB.y, gdy = gC.x, gdz = gC.y;
    float gqx = gD.x, gqy = gD.y, gqz = gE.x, gqw = gE.y;

    float gdiag = sqrtf(gdx * gdx + gdy * gdy + gdz * gdz);
    float corner_scale = 0.2f * 0.125f / (gdiag + 1e-6f);

    // ---- diag + center ----
    float s_diag = fabsf(pdx - gdx) / (gdx + 1e-6f)
                 + fabsf(pdy - gdy) / (gdy + 1e-6f)
                 + fabsf(pdz - gdz) / (gdz + 1e-6f);
    float s_center = (fabsf(px - gx) + fabsf(py - gy) + fabsf(pz - gz)) / gdiag;

    // ---- single rotation matrix per quaternion (eps 1e-8) ----
    float Rp[9], Rg[9];
    quat_mat(pqx, pqy, pqz, pqw, 1e-8f, Rp);
    quat_mat(gqx, gqy, gqz, gqw, 1e-8f, Rg);

    // ---- quat loss ----
    float s_quat = 0.0f;
#pragma unroll
    for (int i = 0; i < 3; ++i) {
      float m = 0.0f;
#pragma unroll
      for (int j = 0; j < 3; ++j) {
        float d = fabsf(Rp[i] * Rg[j] + Rp[3 + i] * Rg[3 + j] +
                        Rp[6 + i] * Rg[6 + j]);
        m = fmaxf(m, d);
      }
      m = fminf(fmaxf(m, 1e-6f), 1.0f);
      s_quat += acos_fast(m);
    }

    // ---- canonical loss ----
    int q0 = 0, q1 = 1, q2 = 2;
    float v0 = pdx, v1 = pdy, v2 = pdz;
    if (v1 > v0) { float t = v0; v0 = v1; v1 = t; int ti = q0; q0 = q1; q1 = ti; }
    if (v2 > v1) { float t = v1; v1 = v2; v2 = t; int ti = q1; q1 = q2; q2 = ti; }
    if (v1 > v0) { float t = v0; v0 = v1; v1 = t; int ti = q0; q0 = q1; q1 = ti; }
    int r0 = 0, r1 = 1, r2 = 2;
    float u0 = gdx, u1 = gdy, u2 = gdz;
    if (u1 > u0) { float t = u0; u0 = u1; u1 = t; int ti = r0; r0 = r1; r1 = ti; }
    if (u2 > u1) { float t = u1; u1 = u2; u2 = t; int ti = r1; r1 = r2; r2 = ti; }
    if (u1 > u0) { float t = u0; u0 = u1; u1 = t; int ti = r0; r0 = r1; r1 = ti; }

    float s_cdims = fabsf(v0 - u0) / (u0 + 1e-8f)
                  + fabsf(v1 - u1) / (u1 + 1e-8f)
                  + fabsf(v2 - u2) / (u2 + 1e-8f);

    int ig0 = (r0 == 0) ? 0 : ((r1 == 0) ? 1 : 2);
    int ig1 = (r0 == 1) ? 0 : ((r1 == 1) ? 1 : 2);
    int ig2 = (r0 == 2) ? 0 : ((r1 == 2) ? 1 : 2);
    int t0 = sel3i(ig0, ig1, ig2, q0);
    int t1 = sel3i(ig0, ig1, ig2, q1);
    int t2 = sel3i(ig0, ig1, ig2, q2);

    float s_cang = 0.0f;
#pragma unroll
    for (int i = 0; i < 3; ++i) {
      float gg0 = Rg[i * 3 + 0], gg1 = Rg[i * 3 + 1], gg2 = Rg[i * 3 + 2];
      float ds = Rp[i * 3 + 0] * sel3(gg0, gg1, gg2, t0)
               + Rp[i * 3 + 1] * sel3(gg0, gg1, gg2, t1)
               + Rp[i * 3 + 2] * sel3(gg0, gg1, gg2, t2);
      float ad = fminf(fabsf(ds), 1.0f);
      s_cang += acos_fast(ad);
    }

    // ---- box bases ----
    float phx = 0.5f * pdx, phy = 0.5f * pdy, phz = 0.5f * pdz;
    float ghx = 0.5f * gdx, ghy = 0.5f * gdy, ghz = 0.5f * gdz;
    float pA0x = Rp[0] * phx, pA0y = Rp[3] * phx, pA0z = Rp[6] * phx;
    float pA1x = Rp[1] * phy, pA1y = Rp[4] * phy, pA1z = Rp[7] * phy;
    float pA2x = Rp[2] * phz, pA2y = Rp[5] * phz, pA2z = Rp[8] * phz;
    float gA0x = Rg[0] * ghx, gA0y = Rg[3] * ghx, gA0z = Rg[6] * ghx;
    float gA1x = Rg[1] * ghy, gA1y = Rg[4] * ghy, gA1z = Rg[7] * ghy;
    float gA2x = Rg[2] * ghz, gA2y = Rg[5] * ghz, gA2z = Rg[8] * ghz;

    // ---- projected IoU via closed-form OBB axis extents
    // (== corner min/max; validated in r11 role A) ----
    float pex = fabsf(pA0x) + fabsf(pA1x) + fabsf(pA2x);
    float pey = fabsf(pA0y) + fabsf(pA1y) + fabsf(pA2y);
    float pez = fabsf(pA0z) + fabsf(pA1z) + fabsf(pA2z);
    float gex = fabsf(gA0x) + fabsf(gA1x) + fabsf(gA2x);
    float gey = fabsf(gA0y) + fabsf(gA1y) + fabsf(gA2y);
    float gez = fabsf(gA0z) + fabsf(gA1z) + fabsf(gA2z);
    float pmnx = px - pex, pmxx = px + pex;
    float pmny = py - pey, pmxy = py + pey;
    float pmnz = pz - pez, pmxz = pz + pez;
    float gmnx = gx - gex, gmxx = gx + gex;
    float gmny = gy - gey, gmxy = gy + gey;
    float gmnz = gz - gez, gmxz = gz + gez;

    auto plane_iou = [&](float a1n, float a1x, float b1n, float b1x,
                         float a2n, float a2x, float b2n, float b2x,
                         float p1n, float p1x, float p2n, float p2x) -> float {
      const float eps = 1e-3f;
      float ia = fmaxf(fminf(a1x, a2x) - fmaxf(a1n, a2n) + eps, 0.0f);
      float ib = fmaxf(fminf(b1x, b2x) - fmaxf(b1n, b2n) + eps, 0.0f);
      float inter = ia * ib;
      float ar1 = (a1x - a1n + eps) * (b1x - b1n + eps);
      float ar2 = (a2x - a2n + eps) * (b2x - b2n + eps);
      float iou2d = inter / (ar1 + ar2 - inter + 1e-6f);
      float hi = fmaxf(fminf(p1x, p2x) - fmaxf(p1n, p2n), 0.0f);
      float hu = (p1x - p1n) + (p2x - p2n) - hi;
      return iou2d * (hi / (hu + 1e-6f));
    };
    float iou_sum = 0.0f;
    iou_sum += plane_iou(pmnx, pmxx, pmnz, pmxz, gmnx, gmxx, gmnz, gmxz,
                         pmny, pmxy, gmny, gmxy);
    iou_sum += plane_iou(pmnx, pmxx, pmny, pmxy, gmnx, gmxx, gmny, gmxy,
                         pmnz, pmxz, gmnz, gmxz);
    iou_sum += plane_iou(pmny, pmxy, pmnz, pmxz, gmny, gmxy, gmnz, gmxz,
                         pmnx, pmxx, gmnx, gmxx);
    float iou_b = fminf(fmaxf(iou_sum * (1.0f / 3.0f), 0.0f), 1.0f);

    // ---- corners (round-2-proven f32 array pattern) ----
    float pcx[8], pcy[8], pcz[8], gcx[8], gcy[8], gcz[8];
#pragma unroll
    for (int k = 0; k < 8; ++k) {
      float sx = (k & 4) ? -1.0f : 1.0f;
      float sy = (k & 2) ? -1.0f : 1.0f;
      float sz = (k & 1) ? -1.0f : 1.0f;
      pcx[k] = px + sx * pA0x + sy * pA1x + sz * pA2x;
      pcy[k] = py + sx * pA0y + sy * pA1y + sz * pA2y;
      pcz[k] = pz + sx * pA0z + sy * pA1z + sz * pA2z;
      gcx[k] = gx + sx * gA0x + sy * gA1x + sz * gA2x;
      gcy[k] = gy + sx * gA0y + sy * gA1y + sz * gA2y;
      gcz[k] = gz + sx * gA0z + sy * gA1z + sz * gA2z;
    }

    // ---- corner assignment: min over 48 signed axis-permutations ----
    float D[8][8];
#pragma unroll
    for (int r = 0; r < 8; ++r)
#pragma unroll
      for (int j = 0; j < 8; ++j)
        D[r][j] = fabsf(pcx[r] - gcx[j]) + fabsf(pcy[r] - gcy[j]) +
                  fabsf(pcz[r] - gcz[j]);

    float best = 3.0e38f;
    static_for<0, 48>([&](auto A) {
      constexpr int p = decltype(A)::value / 8;
      constexpr int m = decltype(A)::value & 7;
      float sum = D[0][permute_bits(0, p) ^ m];
      static_for<1, 8>([&](auto K) {
        constexpr int k = decltype(K)::value;
        sum += D[k][permute_bits(k, p) ^ m];
      });
      best = fminf(best, sum);
    });

    // ---- combine ----
    const float third = (1.0f / 3.0f);
    float loss_b = 0.15f * s_diag * third
                 + 0.2f * s_center * third
                 + 0.15f * s_quat * third
                 + 0.1f * (0.5f * s_cdims * third + 0.5f * s_cang * third)
                 + best * corner_scale
                 - 0.2f * iou_b;
    contrib = loss_b * invB;
  }

  // ---- block reduction: wave shfl -> LDS -> ONE store (no atomic) ----
  float s = contrib;
#pragma unroll
  for (int off = 32; off > 0; off >>= 1) s += __shfl_down(s, off, 64);
  __shared__ float red[BLOCK / 64];
  int lane = threadIdx.x & 63;
  int wid = threadIdx.x >> 6;
  if (lane == 0) red[wid] = s;
  __syncthreads();
  if (threadIdx.x == 0) {
    partials[blockIdx.x] = red[0] + red[1] + red[2] + red[3];
  }
}

// Stage 2: one block reduces the per-block partials; writes out directly
// (replaces the memset dispatch AND the 512 same-address atomics).
__global__ __launch_bounds__(BLOCK)
void reduce_kernel(const float* __restrict__ partials, int n,
                   float* __restrict__ out) {
  float s = 0.0f;
  for (int i = threadIdx.x; i < n; i += BLOCK) s += partials[i];
#pragma unroll
  for (int off = 32; off > 0; off >>= 1) s += __shfl_down(s, off, 64);
  __shared__ float red[BLOCK / 64];
  int lane = threadIdx.x & 63;
  int wid = threadIdx.x >> 6;
  if (lane == 0) red[wid] = s;
  __syncthreads();
  if (threadIdx.x == 0) {
    out[0] = red[0] + red[1] + red[2] + red[3] + 0.2f;  // + W['iou']*1.0
  }
}

extern "C" void kernel_launch(void* const* d_in, const int* in_sizes, int n_in,
                              void* d_out, int out_size, void* d_ws, size_t ws_size,
                              hipStream_t stream) {
  const float* pred = (const float*)d_in[0];
  const float* gt = (const float*)d_in[1];
  float* out = (float*)d_out;
  float* partials = (float*)d_ws;
  int B = in_sizes[0] / 10;
  int grid = (B + BLOCK - 1) / BLOCK;
  hybrid_loss_kernel<<<grid, BLOCK, 0, stream>>>(pred, gt, partials, B,
                                                 1.0f / (float)B);
  reduce_kernel<<<1, BLOCK, 0, stream>>>(partials, grid, out);
}

// Round 13
// 65.823 us; speedup vs baseline: 1.1322x; 1.0200x over previous
//
#include <hip/hip_runtime.h>
#include <math.h>

#define BLOCK 256

// ---------- fast math: single-instruction rcp/sqrt (~1 ulp; our slack is
// 7.8e-3 from the 48-perm assignment, so 2e-7 relative error is free) ----
__device__ __forceinline__ float frcp(float x) {
  return __builtin_amdgcn_rcpf(x);
}
__device__ __forceinline__ float fsqrt(float x) {
  return __builtin_amdgcn_sqrtf(x);
}

// ---------- compile-time machinery ----------
template <int I> struct IC { static constexpr int value = I; };

template <int I, int N, typename F>
__device__ __forceinline__ void static_for(F&& f) {
  if constexpr (I < N) {
    f(IC<I>{});
    static_for<I + 1, N>(f);
  }
}

// corner index bits: bit2 -> x sign, bit1 -> y sign, bit0 -> z sign.
constexpr int permute_bits(int k, int p) {
  int b2 = (k >> 2) & 1, b1 = (k >> 1) & 1, b0 = k & 1;
  switch (p) {
    case 0: return (b2 << 2) | (b1 << 1) | b0;
    case 1: return (b2 << 2) | (b0 << 1) | b1;
    case 2: return (b1 << 2) | (b2 << 1) | b0;
    case 3: return (b1 << 2) | (b0 << 1) | b2;
    case 4: return (b0 << 2) | (b2 << 1) | b1;
    default: return (b0 << 2) | (b1 << 1) | b2;
  }
}

// Abramowitz-Stegun 4.4.45: acos(x) for x in [0,1], |err| <= 6.7e-5 rad.
__device__ __forceinline__ float acos_fast(float x) {
  float r = fsqrt(fmaxf(1.0f - x, 0.0f));
  float p = fmaf(x, -0.0187293f, 0.0742610f);
  p = fmaf(x, p, -0.2121144f);
  p = fmaf(x, p, 1.5707288f);
  return r * p;
}

__device__ __forceinline__ void quat_mat(float x, float y, float z, float w,
                                         float eps, float R[9]) {
  float n = fsqrt(x * x + y * y + z * z + w * w);
  float s = frcp(n + eps);
  x *= s; y *= s; z *= s; w *= s;
  R[0] = 1.0f - 2.0f * y * y - 2.0f * z * z;
  R[1] = 2.0f * x * y - 2.0f * z * w;
  R[2] = 2.0f * x * z + 2.0f * y * w;
  R[3] = 2.0f * x * y + 2.0f * z * w;
  R[4] = 1.0f - 2.0f * x * x - 2.0f * z * z;
  R[5] = 2.0f * y * z - 2.0f * x * w;
  R[6] = 2.0f * x * z - 2.0f * y * w;
  R[7] = 2.0f * y * z + 2.0f * x * w;
  R[8] = 1.0f - 2.0f * x * x - 2.0f * y * y;
}

__device__ __forceinline__ float sel3(float v0, float v1, float v2, int i) {
  return i == 0 ? v0 : (i == 1 ? v1 : v2);
}
__device__ __forceinline__ int sel3i(int v0, int v1, int v2, int i) {
  return i == 0 ? v0 : (i == 1 ? v1 : v2);
}

// Stage 1: per-box loss, block partial -> d_ws[blockIdx] (no atomics).
__global__ __launch_bounds__(BLOCK)
void hybrid_loss_kernel(const float* __restrict__ pred,
                        const float* __restrict__ gt,
                        float* __restrict__ partials, int B, float invB) {
  int b = blockIdx.x * BLOCK + threadIdx.x;
  float contrib = 0.0f;
  if (b < B) {
    // ---- load (rows are 40B, 8-byte aligned -> five float2 loads each) ----
    const float2* p2 = reinterpret_cast<const float2*>(pred) + (size_t)b * 5;
    const float2* g2 = reinterpret_cast<const float2*>(gt) + (size_t)b * 5;
    float2 pA = p2[0], pB = p2[1], pC = p2[2], pD = p2[3], pE = p2[4];
    float2 gA = g2[0], gB = g2[1], gC = g2[2], gD = g2[3], gE = g2[4];
    float px = pA.x, py = pA.y, pz = pB.x;
    float pdx = pB.y, pdy = pC.x, pdz = pC.y;
    float pqx = pD.x, pqy = pD.y, pqz = pE.x, pqw = pE.y;
    float gx = gA.x, gy = gA.y, gz = gB.x;
    float gdx = gB.y, gdy = gC.x, gdz = gC.y;
    float gqx = gD.x, gqy = gD.y, gqz = gE.x, gqw = gE.y;

    float gdiag = fsqrt(gdx * gdx + gdy * gdy + gdz * gdz);
    float rgdiag = frcp(gdiag);
    float corner_scale = 0.2f * 0.125f * frcp(gdiag + 1e-6f);

    // ---- diag + center ----
    float s_diag = fabsf(pdx - gdx) * frcp(gdx + 1e-6f)
                 + fabsf(pdy - gdy) * frcp(gdy + 1e-6f)
                 + fabsf(pdz - gdz) * frcp(gdz + 1e-6f);
    float s_center =
        (fabsf(px - gx) + fabsf(py - gy) + fabsf(pz - gz)) * rgdiag;

    // ---- single rotation matrix per quaternion (eps 1e-8) ----
    float Rp[9], Rg[9];
    quat_mat(pqx, pqy, pqz, pqw, 1e-8f, Rp);
    quat_mat(gqx, gqy, gqz, gqw, 1e-8f, Rg);

    // ---- quat loss ----
    float s_quat = 0.0f;
#pragma unroll
    for (int i = 0; i < 3; ++i) {
      float m = 0.0f;
#pragma unroll
      for (int j = 0; j < 3; ++j) {
        float d = fabsf(Rp[i] * Rg[j] + Rp[3 + i] * Rg[3 + j] +
                        Rp[6 + i] * Rg[6 + j]);
        m = fmaxf(m, d);
      }
      m = fminf(fmaxf(m, 1e-6f), 1.0f);
      s_quat += acos_fast(m);
    }

    // ---- canonical loss ----
    int q0 = 0, q1 = 1, q2 = 2;
    float v0 = pdx, v1 = pdy, v2 = pdz;
    if (v1 > v0) { float t = v0; v0 = v1; v1 = t; int ti = q0; q0 = q1; q1 = ti; }
    if (v2 > v1) { float t = v1; v1 = v2; v2 = t; int ti = q1; q1 = q2; q2 = ti; }
    if (v1 > v0) { float t = v0; v0 = v1; v1 = t; int ti = q0; q0 = q1; q1 = ti; }
    int r0 = 0, r1 = 1, r2 = 2;
    float u0 = gdx, u1 = gdy, u2 = gdz;
    if (u1 > u0) { float t = u0; u0 = u1; u1 = t; int ti = r0; r0 = r1; r1 = ti; }
    if (u2 > u1) { float t = u1; u1 = u2; u2 = t; int ti = r1; r1 = r2; r2 = ti; }
    if (u1 > u0) { float t = u0; u0 = u1; u1 = t; int ti = r0; r0 = r1; r1 = ti; }

    float s_cdims = fabsf(v0 - u0) * frcp(u0 + 1e-8f)
                  + fabsf(v1 - u1) * frcp(u1 + 1e-8f)
                  + fabsf(v2 - u2) * frcp(u2 + 1e-8f);

    int ig0 = (r0 == 0) ? 0 : ((r1 == 0) ? 1 : 2);
    int ig1 = (r0 == 1) ? 0 : ((r1 == 1) ? 1 : 2);
    int ig2 = (r0 == 2) ? 0 : ((r1 == 2) ? 1 : 2);
    int t0 = sel3i(ig0, ig1, ig2, q0);
    int t1 = sel3i(ig0, ig1, ig2, q1);
    int t2 = sel3i(ig0, ig1, ig2, q2);

    float s_cang = 0.0f;
#pragma unroll
    for (int i = 0; i < 3; ++i) {
      float gg0 = Rg[i * 3 + 0], gg1 = Rg[i * 3 + 1], gg2 = Rg[i * 3 + 2];
      float ds = Rp[i * 3 + 0] * sel3(gg0, gg1, gg2, t0)
               + Rp[i * 3 + 1] * sel3(gg0, gg1, gg2, t1)
               + Rp[i * 3 + 2] * sel3(gg0, gg1, gg2, t2);
      float ad = fminf(fabsf(ds), 1.0f);
      s_cang += acos_fast(ad);
    }

    // ---- box bases ----
    float phx = 0.5f * pdx, phy = 0.5f * pdy, phz = 0.5f * pdz;
    float ghx = 0.5f * gdx, ghy = 0.5f * gdy, ghz = 0.5f * gdz;
    float pA0x = Rp[0] * phx, pA0y = Rp[3] * phx, pA0z = Rp[6] * phx;
    float pA1x = Rp[1] * phy, pA1y = Rp[4] * phy, pA1z = Rp[7] * phy;
    float pA2x = Rp[2] * phz, pA2y = Rp[5] * phz, pA2z = Rp[8] * phz;
    float gA0x = Rg[0] * ghx, gA0y = Rg[3] * ghx, gA0z = Rg[6] * ghx;
    float gA1x = Rg[1] * ghy, gA1y = Rg[4] * ghy, gA1z = Rg[7] * ghy;
    float gA2x = Rg[2] * ghz, gA2y = Rg[5] * ghz, gA2z = Rg[8] * ghz;

    // ---- projected IoU via closed-form OBB axis extents ----
    float pex = fabsf(pA0x) + fabsf(pA1x) + fabsf(pA2x);
    float pey = fabsf(pA0y) + fabsf(pA1y) + fabsf(pA2y);
    float pez = fabsf(pA0z) + fabsf(pA1z) + fabsf(pA2z);
    float gex = fabsf(gA0x) + fabsf(gA1x) + fabsf(gA2x);
    float gey = fabsf(gA0y) + fabsf(gA1y) + fabsf(gA2y);
    float gez = fabsf(gA0z) + fabsf(gA1z) + fabsf(gA2z);
    float pmnx = px - pex, pmxx = px + pex;
    float pmny = py - pey, pmxy = py + pey;
    float pmnz = pz - pez, pmxz = pz + pez;
    float gmnx = gx - gex, gmxx = gx + gex;
    float gmny = gy - gey, gmxy = gy + gey;
    float gmnz = gz - gez, gmxz = gz + gez;

    auto plane_iou = [&](float a1n, float a1x, float b1n, float b1x,
                         float a2n, float a2x, float b2n, float b2x,
                         float p1n, float p1x, float p2n, float p2x) -> float {
      const float eps = 1e-3f;
      float ia = fmaxf(fminf(a1x, a2x) - fmaxf(a1n, a2n) + eps, 0.0f);
      float ib = fmaxf(fminf(b1x, b2x) - fmaxf(b1n, b2n) + eps, 0.0f);
      float inter = ia * ib;
      float ar1 = (a1x - a1n + eps) * (b1x - b1n + eps);
      float ar2 = (a2x - a2n + eps) * (b2x - b2n + eps);
      float iou2d = inter * frcp(ar1 + ar2 - inter + 1e-6f);
      float hi = fmaxf(fminf(p1x, p2x) - fmaxf(p1n, p2n), 0.0f);
      float hu = (p1x - p1n) + (p2x - p2n) - hi;
      return iou2d * (hi * frcp(hu + 1e-6f));
    };
    float iou_sum = 0.0f;
    iou_sum += plane_iou(pmnx, pmxx, pmnz, pmxz, gmnx, gmxx, gmnz, gmxz,
                         pmny, pmxy, gmny, gmxy);
    iou_sum += plane_iou(pmnx, pmxx, pmny, pmxy, gmnx, gmxx, gmny, gmxy,
                         pmnz, pmxz, gmnz, gmxz);
    iou_sum += plane_iou(pmny, pmxy, pmnz, pmxz, gmny, gmxy, gmnz, gmxz,
                         pmnx, pmxx, gmnx, gmxx);
    float iou_b = fminf(fmaxf(iou_sum * (1.0f / 3.0f), 0.0f), 1.0f);

    // ---- corners (round-2-proven f32 array pattern) ----
    float pcx[8], pcy[8], pcz[8], gcx[8], gcy[8], gcz[8];
#pragma unroll
    for (int k = 0; k < 8; ++k) {
      float sx = (k & 4) ? -1.0f : 1.0f;
      float sy = (k & 2) ? -1.0f : 1.0f;
      float sz = (k & 1) ? -1.0f : 1.0f;
      pcx[k] = px + sx * pA0x + sy * pA1x + sz * pA2x;
      pcy[k] = py + sx * pA0y + sy * pA1y + sz * pA2y;
      pcz[k] = pz + sx * pA0z + sy * pA1z + sz * pA2z;
      gcx[k] = gx + sx * gA0x + sy * gA1x + sz * gA2x;
      gcy[k] = gy + sx * gA0y + sy * gA1y + sz * gA2y;
      gcz[k] = gz + sx * gA0z + sy * gA1z + sz * gA2z;
    }

    // ---- corner assignment: min over 48 signed axis-permutations ----
    float D[8][8];
#pragma unroll
    for (int r = 0; r < 8; ++r)
#pragma unroll
      for (int j = 0; j < 8; ++j)
        D[r][j] = fabsf(pcx[r] - gcx[j]) + fabsf(pcy[r] - gcy[j]) +
                  fabsf(pcz[r] - gcz[j]);

    float best = 3.0e38f;
    static_for<0, 48>([&](auto A) {
      constexpr int p = decltype(A)::value / 8;
      constexpr int m = decltype(A)::value & 7;
      float sum = D[0][permute_bits(0, p) ^ m];
      static_for<1, 8>([&](auto K) {
        constexpr int k = decltype(K)::value;
        sum += D[k][permute_bits(k, p) ^ m];
      });
      best = fminf(best, sum);
    });

    // ---- combine ----
    const float third = (1.0f / 3.0f);
    float loss_b = 0.15f * s_diag * third
                 + 0.2f * s_center * third
                 + 0.15f * s_quat * third
                 + 0.1f * (0.5f * s_cdims * third + 0.5f * s_cang * third)
                 + best * corner_scale
                 - 0.2f * iou_b;
    contrib = loss_b * invB;
  }

  // ---- block reduction: wave shfl -> LDS -> ONE store (no atomic) ----
  float s = contrib;
#pragma unroll
  for (int off = 32; off > 0; off >>= 1) s += __shfl_down(s, off, 64);
  __shared__ float red[BLOCK / 64];
  int lane = threadIdx.x & 63;
  int wid = threadIdx.x >> 6;
  if (lane == 0) red[wid] = s;
  __syncthreads();
  if (threadIdx.x == 0) {
    partials[blockIdx.x] = red[0] + red[1] + red[2] + red[3];
  }
}

// Stage 2: one block reduces the per-block partials; writes out directly.
__global__ __launch_bounds__(BLOCK)
void reduce_kernel(const float* __restrict__ partials, int n,
                   float* __restrict__ out) {
  float s = 0.0f;
  for (int i = threadIdx.x; i < n; i += BLOCK) s += partials[i];
#pragma unroll
  for (int off = 32; off > 0; off >>= 1) s += __shfl_down(s, off, 64);
  __shared__ float red[BLOCK / 64];
  int lane = threadIdx.x & 63;
  int wid = threadIdx.x >> 6;
  if (lane == 0) red[wid] = s;
  __syncthreads();
  if (threadIdx.x == 0) {
    out[0] = red[0] + red[1] + red[2] + red[3] + 0.2f;  // + W['iou']*1.0
  }
}

extern "C" void kernel_launch(void* const* d_in, const int* in_sizes, int n_in,
                              void* d_out, int out_size, void* d_ws, size_t ws_size,
                              hipStream_t stream) {
  const float* pred = (const float*)d_in[0];
  const float* gt = (const float*)d_in[1];
  float* out = (float*)d_out;
  float* partials = (float*)d_ws;
  int B = in_sizes[0] / 10;
  int grid = (B + BLOCK - 1) / BLOCK;
  hybrid_loss_kernel<<<grid, BLOCK, 0, stream>>>(pred, gt, partials, B,
                                                 1.0f / (float)B);
  reduce_kernel<<<1, BLOCK, 0, stream>>>(partials, grid, out);
}

// Round 14
// 64.778 us; speedup vs baseline: 1.1505x; 1.0161x over previous
//
#include <hip/hip_runtime.h>
#include <math.h>

#define BLOCK 256

// ---------- fast math: single-instruction rcp/sqrt (~1 ulp; our slack is
// 7.8e-3 from the 48-perm assignment, so 2e-7 relative error is free) ----
__device__ __forceinline__ float frcp(float x) {
  return __builtin_amdgcn_rcpf(x);
}
__device__ __forceinline__ float fsqrt(float x) {
  return __builtin_amdgcn_sqrtf(x);
}

// ---------- compile-time machinery ----------
template <int I> struct IC { static constexpr int value = I; };

template <int I, int N, typename F>
__device__ __forceinline__ void static_for(F&& f) {
  if constexpr (I < N) {
    f(IC<I>{});
    static_for<I + 1, N>(f);
  }
}

// corner index bits: bit2 -> x sign, bit1 -> y sign, bit0 -> z sign.
constexpr int permute_bits(int k, int p) {
  int b2 = (k >> 2) & 1, b1 = (k >> 1) & 1, b0 = k & 1;
  switch (p) {
    case 0: return (b2 << 2) | (b1 << 1) | b0;
    case 1: return (b2 << 2) | (b0 << 1) | b1;
    case 2: return (b1 << 2) | (b2 << 1) | b0;
    case 3: return (b1 << 2) | (b0 << 1) | b2;
    case 4: return (b0 << 2) | (b2 << 1) | b1;
    default: return (b0 << 2) | (b1 << 1) | b2;
  }
}

// Abramowitz-Stegun 4.4.45: acos(x) for x in [0,1], |err| <= 6.7e-5 rad.
__device__ __forceinline__ float acos_fast(float x) {
  float r = fsqrt(fmaxf(1.0f - x, 0.0f));
  float p = fmaf(x, -0.0187293f, 0.0742610f);
  p = fmaf(x, p, -0.2121144f);
  p = fmaf(x, p, 1.5707288f);
  return r * p;
}

__device__ __forceinline__ void quat_mat(float x, float y, float z, float w,
                                         float eps, float R[9]) {
  float n = fsqrt(x * x + y * y + z * z + w * w);
  float s = frcp(n + eps);
  x *= s; y *= s; z *= s; w *= s;
  R[0] = 1.0f - 2.0f * y * y - 2.0f * z * z;
  R[1] = 2.0f * x * y - 2.0f * z * w;
  R[2] = 2.0f * x * z + 2.0f * y * w;
  R[3] = 2.0f * x * y + 2.0f * z * w;
  R[4] = 1.0f - 2.0f * x * x - 2.0f * z * z;
  R[5] = 2.0f * y * z - 2.0f * x * w;
  R[6] = 2.0f * x * z - 2.0f * y * w;
  R[7] = 2.0f * y * z + 2.0f * x * w;
  R[8] = 1.0f - 2.0f * x * x - 2.0f * y * y;
}

__device__ __forceinline__ float sel3(float v0, float v1, float v2, int i) {
  return i == 0 ? v0 : (i == 1 ? v1 : v2);
}
__device__ __forceinline__ int sel3i(int v0, int v1, int v2, int i) {
  return i == 0 ? v0 : (i == 1 ? v1 : v2);
}

// Stage 1: per-box loss, block partial -> d_ws[blockIdx] (no atomics).
__global__ __launch_bounds__(BLOCK)
void hybrid_loss_kernel(const float* __restrict__ pred,
                        const float* __restrict__ gt,
                        float* __restrict__ partials, int B, float invB) {
  int b = blockIdx.x * BLOCK + threadIdx.x;
  float contrib = 0.0f;
  if (b < B) {
    // ---- load (rows are 40B, 8-byte aligned -> five float2 loads each) ----
    const float2* p2 = reinterpret_cast<const float2*>(pred) + (size_t)b * 5;
    const float2* g2 = reinterpret_cast<const float2*>(gt) + (size_t)b * 5;
    float2 pA = p2[0], pB = p2[1], pC = p2[2], pD = p2[3], pE = p2[4];
    float2 gA = g2[0], gB = g2[1], gC = g2[2], gD = g2[3], gE = g2[4];
    float px = pA.x, py = pA.y, pz = pB.x;
    float pdx = pB.y, pdy = pC.x, pdz = pC.y;
    float pqx = pD.x, pqy = pD.y, pqz = pE.x, pqw = pE.y;
    float gx = gA.x, gy = gA.y, gz = gB.x;
    float gdx = gB.y, gdy = gC.x, gdz = gC.y;
    float gqx = gD.x, gqy = gD.y, gqz = gE.x, gqw = gE.y;

    float gdiag = fsqrt(gdx * gdx + gdy * gdy + gdz * gdz);
    float rgdiag = frcp(gdiag);
    float corner_scale = 0.2f * 0.125f * frcp(gdiag + 1e-6f);

    // ---- diag + center ----
    float s_diag = fabsf(pdx - gdx) * frcp(gdx + 1e-6f)
                 + fabsf(pdy - gdy) * frcp(gdy + 1e-6f)
                 + fabsf(pdz - gdz) * frcp(gdz + 1e-6f);
    float s_center =
        (fabsf(px - gx) + fabsf(py - gy) + fabsf(pz - gz)) * rgdiag;

    // ---- single rotation matrix per quaternion (eps 1e-8) ----
    float Rp[9], Rg[9];
    quat_mat(pqx, pqy, pqz, pqw, 1e-8f, Rp);
    quat_mat(gqx, gqy, gqz, gqw, 1e-8f, Rg);

    // ---- quat loss ----
    float s_quat = 0.0f;
#pragma unroll
    for (int i = 0; i < 3; ++i) {
      float m = 0.0f;
#pragma unroll
      for (int j = 0; j < 3; ++j) {
        float d = fabsf(Rp[i] * Rg[j] + Rp[3 + i] * Rg[3 + j] +
                        Rp[6 + i] * Rg[6 + j]);
        m = fmaxf(m, d);
      }
      m = fminf(fmaxf(m, 1e-6f), 1.0f);
      s_quat += acos_fast(m);
    }

    // ---- canonical loss ----
    int q0 = 0, q1 = 1, q2 = 2;
    float v0 = pdx, v1 = pdy, v2 = pdz;
    if (v1 > v0) { float t = v0; v0 = v1; v1 = t; int ti = q0; q0 = q1; q1 = ti; }
    if (v2 > v1) { float t = v1; v1 = v2; v2 = t; int ti = q1; q1 = q2; q2 = ti; }
    if (v1 > v0) { float t = v0; v0 = v1; v1 = t; int ti = q0; q0 = q1; q1 = ti; }
    int r0 = 0, r1 = 1, r2 = 2;
    float u0 = gdx, u1 = gdy, u2 = gdz;
    if (u1 > u0) { float t = u0; u0 = u1; u1 = t; int ti = r0; r0 = r1; r1 = ti; }
    if (u2 > u1) { float t = u1; u1 = u2; u2 = t; int ti = r1; r1 = r2; r2 = ti; }
    if (u1 > u0) { float t = u0; u0 = u1; u1 = t; int ti = r0; r0 = r1; r1 = ti; }

    float s_cdims = fabsf(v0 - u0) * frcp(u0 + 1e-8f)
                  + fabsf(v1 - u1) * frcp(u1 + 1e-8f)
                  + fabsf(v2 - u2) * frcp(u2 + 1e-8f);

    int ig0 = (r0 == 0) ? 0 : ((r1 == 0) ? 1 : 2);
    int ig1 = (r0 == 1) ? 0 : ((r1 == 1) ? 1 : 2);
    int ig2 = (r0 == 2) ? 0 : ((r1 == 2) ? 1 : 2);
    int t0 = sel3i(ig0, ig1, ig2, q0);
    int t1 = sel3i(ig0, ig1, ig2, q1);
    int t2 = sel3i(ig0, ig1, ig2, q2);

    float s_cang = 0.0f;
#pragma unroll
    for (int i = 0; i < 3; ++i) {
      float gg0 = Rg[i * 3 + 0], gg1 = Rg[i * 3 + 1], gg2 = Rg[i * 3 + 2];
      float ds = Rp[i * 3 + 0] * sel3(gg0, gg1, gg2, t0)
               + Rp[i * 3 + 1] * sel3(gg0, gg1, gg2, t1)
               + Rp[i * 3 + 2] * sel3(gg0, gg1, gg2, t2);
      float ad = fminf(fabsf(ds), 1.0f);
      s_cang += acos_fast(ad);
    }

    // ---- box bases ----
    float phx = 0.5f * pdx, phy = 0.5f * pdy, phz = 0.5f * pdz;
    float ghx = 0.5f * gdx, ghy = 0.5f * gdy, ghz = 0.5f * gdz;
    float pA0x = Rp[0] * phx, pA0y = Rp[3] * phx, pA0z = Rp[6] * phx;
    float pA1x = Rp[1] * phy, pA1y = Rp[4] * phy, pA1z = Rp[7] * phy;
    float pA2x = Rp[2] * phz, pA2y = Rp[5] * phz, pA2z = Rp[8] * phz;
    float gA0x = Rg[0] * ghx, gA0y = Rg[3] * ghx, gA0z = Rg[6] * ghx;
    float gA1x = Rg[1] * ghy, gA1y = Rg[4] * ghy, gA1z = Rg[7] * ghy;
    float gA2x = Rg[2] * ghz, gA2y = Rg[5] * ghz, gA2z = Rg[8] * ghz;

    // ---- projected IoU via closed-form OBB axis extents ----
    float pex = fabsf(pA0x) + fabsf(pA1x) + fabsf(pA2x);
    float pey = fabsf(pA0y) + fabsf(pA1y) + fabsf(pA2y);
    float pez = fabsf(pA0z) + fabsf(pA1z) + fabsf(pA2z);
    float gex = fabsf(gA0x) + fabsf(gA1x) + fabsf(gA2x);
    float gey = fabsf(gA0y) + fabsf(gA1y) + fabsf(gA2y);
    float gez = fabsf(gA0z) + fabsf(gA1z) + fabsf(gA2z);
    float pmnx = px - pex, pmxx = px + pex;
    float pmny = py - pey, pmxy = py + pey;
    float pmnz = pz - pez, pmxz = pz + pez;
    float gmnx = gx - gex, gmxx = gx + gex;
    float gmny = gy - gey, gmxy = gy + gey;
    float gmnz = gz - gez, gmxz = gz + gez;

    auto plane_iou = [&](float a1n, float a1x, float b1n, float b1x,
                         float a2n, float a2x, float b2n, float b2x,
                         float p1n, float p1x, float p2n, float p2x) -> float {
      const float eps = 1e-3f;
      float ia = fmaxf(fminf(a1x, a2x) - fmaxf(a1n, a2n) + eps, 0.0f);
      float ib = fmaxf(fminf(b1x, b2x) - fmaxf(b1n, b2n) + eps, 0.0f);
      float inter = ia * ib;
      float ar1 = (a1x - a1n + eps) * (b1x - b1n + eps);
      float ar2 = (a2x - a2n + eps) * (b2x - b2n + eps);
      float iou2d = inter * frcp(ar1 + ar2 - inter + 1e-6f);
      float hi = fmaxf(fminf(p1x, p2x) - fmaxf(p1n, p2n), 0.0f);
      float hu = (p1x - p1n) + (p2x - p2n) - hi;
      return iou2d * (hi * frcp(hu + 1e-6f));
    };
    float iou_sum = 0.0f;
    iou_sum += plane_iou(pmnx, pmxx, pmnz, pmxz, gmnx, gmxx, gmnz, gmxz,
                         pmny, pmxy, gmny, gmxy);
    iou_sum += plane_iou(pmnx, pmxx, pmny, pmxy, gmnx, gmxx, gmny, gmxy,
                         pmnz, pmxz, gmnz, gmxz);
    iou_sum += plane_iou(pmny, pmxy, pmnz, pmxz, gmny, gmxy, gmnz, gmxz,
                         pmnx, pmxx, gmnx, gmxx);
    float iou_b = fminf(fmaxf(iou_sum * (1.0f / 3.0f), 0.0f), 1.0f);

    // ---- corners (round-2-proven f32 array pattern) ----
    float pcx[8], pcy[8], pcz[8], gcx[8], gcy[8], gcz[8];
#pragma unroll
    for (int k = 0; k < 8; ++k) {
      float sx = (k & 4) ? -1.0f : 1.0f;
      float sy = (k & 2) ? -1.0f : 1.0f;
      float sz = (k & 1) ? -1.0f : 1.0f;
      pcx[k] = px + sx * pA0x + sy * pA1x + sz * pA2x;
      pcy[k] = py + sx * pA0y + sy * pA1y + sz * pA2y;
      pcz[k] = pz + sx * pA0z + sy * pA1z + sz * pA2z;
      gcx[k] = gx + sx * gA0x + sy * gA1x + sz * gA2x;
      gcy[k] = gy + sx * gA0y + sy * gA1y + sz * gA2y;
      gcz[k] = gz + sx * gA0z + sy * gA1z + sz * gA2z;
    }

    // ---- corner assignment: min over 48 signed axis-permutations.
    // ILP restructure vs r13: balanced 3-deep sums (was 8-deep serial) and
    // 12 independent min accumulators (was one 48-deep serial fminf chain).
    // Pure expression reassociation — same value set, no arrays added. ----
    float D[8][8];
#pragma unroll
    for (int r = 0; r < 8; ++r)
#pragma unroll
      for (int j = 0; j < 8; ++j)
        D[r][j] = fabsf(pcx[r] - gcx[j]) + fabsf(pcy[r] - gcy[j]) +
                  fabsf(pcz[r] - gcz[j]);

    float best = 3.0e38f;
    static_for<0, 6>([&](auto P) {
      constexpr int p = decltype(P)::value;
      float bp0 = 3.0e38f, bp1 = 3.0e38f;  // even/odd m accumulators
      static_for<0, 8>([&](auto M) {
        constexpr int m = decltype(M)::value;
        float s01 = D[0][permute_bits(0, p) ^ m] + D[1][permute_bits(1, p) ^ m];
        float s23 = D[2][permute_bits(2, p) ^ m] + D[3][permute_bits(3, p) ^ m];
        float s45 = D[4][permute_bits(4, p) ^ m] + D[5][permute_bits(5, p) ^ m];
        float s67 = D[6][permute_bits(6, p) ^ m] + D[7][permute_bits(7, p) ^ m];
        float sum = (s01 + s23) + (s45 + s67);
        if constexpr (m & 1) bp1 = fminf(bp1, sum);
        else bp0 = fminf(bp0, sum);
      });
      best = fminf(best, fminf(bp0, bp1));
    });

    // ---- combine ----
    const float third = (1.0f / 3.0f);
    float loss_b = 0.15f * s_diag * third
                 + 0.2f * s_center * third
                 + 0.15f * s_quat * third
                 + 0.1f * (0.5f * s_cdims * third + 0.5f * s_cang * third)
                 + best * corner_scale
                 - 0.2f * iou_b;
    contrib = loss_b * invB;
  }

  // ---- block reduction: wave shfl -> LDS -> ONE store (no atomic) ----
  float s = contrib;
#pragma unroll
  for (int off = 32; off > 0; off >>= 1) s += __shfl_down(s, off, 64);
  __shared__ float red[BLOCK / 64];
  int lane = threadIdx.x & 63;
  int wid = threadIdx.x >> 6;
  if (lane == 0) red[wid] = s;
  __syncthreads();
  if (threadIdx.x == 0) {
    partials[blockIdx.x] = red[0] + red[1] + red[2] + red[3];
  }
}

// Stage 2: one block reduces the per-block partials; writes out directly.
__global__ __launch_bounds__(BLOCK)
void reduce_kernel(const float* __restrict__ partials, int n,
                   float* __restrict__ out) {
  float s = 0.0f;
  for (int i = threadIdx.x; i < n; i += BLOCK) s += partials[i];
#pragma unroll
  for (int off = 32; off > 0; off >>= 1) s += __shfl_down(s, off, 64);
  __shared__ float red[BLOCK / 64];
  int lane = threadIdx.x & 63;
  int wid = threadIdx.x >> 6;
  if (lane == 0) red[wid] = s;
  __syncthreads();
  if (threadIdx.x == 0) {
    out[0] = red[0] + red[1] + red[2] + red[3] + 0.2f;  // + W['iou']*1.0
  }
}

extern "C" void kernel_launch(void* const* d_in, const int* in_sizes, int n_in,
                              void* d_out, int out_size, void* d_ws, size_t ws_size,
                              hipStream_t stream) {
  const float* pred = (const float*)d_in[0];
  const float* gt = (const float*)d_in[1];
  float* out = (float*)d_out;
  float* partials = (float*)d_ws;
  int B = in_sizes[0] / 10;
  int grid = (B + BLOCK - 1) / BLOCK;
  hybrid_loss_kernel<<<grid, BLOCK, 0, stream>>>(pred, gt, partials, B,
                                                 1.0f / (float)B);
  reduce_kernel<<<1, BLOCK, 0, stream>>>(partials, grid, out);
}

// Round 15
// 63.783 us; speedup vs baseline: 1.1685x; 1.0156x over previous
//
#include <hip/hip_runtime.h>
#include <math.h>

#define BLOCK 256

// packed fp16 pair: two adjacent gt-corner columns {even j, odd j}
typedef _Float16 h2 __attribute__((ext_vector_type(2)));

// ---------- fast math: single-instruction rcp/sqrt (~1 ulp) ----------
__device__ __forceinline__ float frcp(float x) {
  return __builtin_amdgcn_rcpf(x);
}
__device__ __forceinline__ float fsqrt(float x) {
  return __builtin_amdgcn_sqrtf(x);
}

// ---------- compile-time machinery ----------
template <int I> struct IC { static constexpr int value = I; };

template <int I, int N, typename F>
__device__ __forceinline__ void static_for(F&& f) {
  if constexpr (I < N) {
    f(IC<I>{});
    static_for<I + 1, N>(f);
  }
}

// corner index bits: bit2 -> x sign, bit1 -> y sign, bit0 -> z sign.
constexpr int permute_bits(int k, int p) {
  int b2 = (k >> 2) & 1, b1 = (k >> 1) & 1, b0 = k & 1;
  switch (p) {
    case 0: return (b2 << 2) | (b1 << 1) | b0;
    case 1: return (b2 << 2) | (b0 << 1) | b1;
    case 2: return (b1 << 2) | (b2 << 1) | b0;
    case 3: return (b1 << 2) | (b0 << 1) | b2;
    case 4: return (b0 << 2) | (b2 << 1) | b1;
    default: return (b0 << 2) | (b1 << 1) | b2;
  }
}

// For pairing (k, j=perm_p(k)^m) with the mask pair {m, m^1}: the two D
// entries needed are {D[k][j], D[k][j^1]} — exactly the h2 cell j>>1,
// half-swapped when j is odd. The shufflevector folds into op_sel (free).
template <int K, int P, int M>
__device__ __forceinline__ h2 pair_term(const h2 (&D2)[8][4]) {
  constexpr int j = permute_bits(K, P) ^ M;
  h2 v = D2[K][j >> 1];
  if constexpr (j & 1)
    return __builtin_shufflevector(v, v, 1, 0);
  else
    return v;
}

// Abramowitz-Stegun 4.4.45: acos(x) for x in [0,1], |err| <= 6.7e-5 rad.
__device__ __forceinline__ float acos_fast(float x) {
  float r = fsqrt(fmaxf(1.0f - x, 0.0f));
  float p = fmaf(x, -0.0187293f, 0.0742610f);
  p = fmaf(x, p, -0.2121144f);
  p = fmaf(x, p, 1.5707288f);
  return r * p;
}

__device__ __forceinline__ void quat_mat(float x, float y, float z, float w,
                                         float eps, float R[9]) {
  float n = fsqrt(x * x + y * y + z * z + w * w);
  float s = frcp(n + eps);
  x *= s; y *= s; z *= s; w *= s;
  R[0] = 1.0f - 2.0f * y * y - 2.0f * z * z;
  R[1] = 2.0f * x * y - 2.0f * z * w;
  R[2] = 2.0f * x * z + 2.0f * y * w;
  R[3] = 2.0f * x * y + 2.0f * z * w;
  R[4] = 1.0f - 2.0f * x * x - 2.0f * z * z;
  R[5] = 2.0f * y * z - 2.0f * x * w;
  R[6] = 2.0f * x * z - 2.0f * y * w;
  R[7] = 2.0f * y * z + 2.0f * x * w;
  R[8] = 1.0f - 2.0f * x * x - 2.0f * y * y;
}

__device__ __forceinline__ float sel3(float v0, float v1, float v2, int i) {
  return i == 0 ? v0 : (i == 1 ? v1 : v2);
}
__device__ __forceinline__ int sel3i(int v0, int v1, int v2, int i) {
  return i == 0 ? v0 : (i == 1 ? v1 : v2);
}

// Stage 1: per-box loss, block partial -> d_ws[blockIdx] (no atomics).
__global__ __launch_bounds__(BLOCK)
void hybrid_loss_kernel(const float* __restrict__ pred,
                        const float* __restrict__ gt,
                        float* __restrict__ partials, int B, float invB) {
  int b = blockIdx.x * BLOCK + threadIdx.x;
  float contrib = 0.0f;
  if (b < B) {
    // ---- load (rows are 40B, 8-byte aligned -> five float2 loads each) ----
    const float2* p2 = reinterpret_cast<const float2*>(pred) + (size_t)b * 5;
    const float2* g2 = reinterpret_cast<const float2*>(gt) + (size_t)b * 5;
    float2 pA = p2[0], pB = p2[1], pC = p2[2], pD = p2[3], pE = p2[4];
    float2 gA = g2[0], gB = g2[1], gC = g2[2], gD = g2[3], gE = g2[4];
    float px = pA.x, py = pA.y, pz = pB.x;
    float pdx = pB.y, pdy = pC.x, pdz = pC.y;
    float pqx = pD.x, pqy = pD.y, pqz = pE.x, pqw = pE.y;
    float gx = gA.x, gy = gA.y, gz = gB.x;
    float gdx = gB.y, gdy = gC.x, gdz = gC.y;
    float gqx = gD.x, gqy = gD.y, gqz = gE.x, gqw = gE.y;

    float gdiag = fsqrt(gdx * gdx + gdy * gdy + gdz * gdz);
    float rgdiag = frcp(gdiag);
    float corner_scale = 0.2f * 0.125f * frcp(gdiag + 1e-6f);

    // ---- diag + center ----
    float s_diag = fabsf(pdx - gdx) * frcp(gdx + 1e-6f)
                 + fabsf(pdy - gdy) * frcp(gdy + 1e-6f)
                 + fabsf(pdz - gdz) * frcp(gdz + 1e-6f);
    float s_center =
        (fabsf(px - gx) + fabsf(py - gy) + fabsf(pz - gz)) * rgdiag;

    // ---- single rotation matrix per quaternion (eps 1e-8) ----
    float Rp[9], Rg[9];
    quat_mat(pqx, pqy, pqz, pqw, 1e-8f, Rp);
    quat_mat(gqx, gqy, gqz, gqw, 1e-8f, Rg);

    // ---- quat loss ----
    float s_quat = 0.0f;
#pragma unroll
    for (int i = 0; i < 3; ++i) {
      float m = 0.0f;
#pragma unroll
      for (int j = 0; j < 3; ++j) {
        float d = fabsf(Rp[i] * Rg[j] + Rp[3 + i] * Rg[3 + j] +
                        Rp[6 + i] * Rg[6 + j]);
        m = fmaxf(m, d);
      }
      m = fminf(fmaxf(m, 1e-6f), 1.0f);
      s_quat += acos_fast(m);
    }

    // ---- canonical loss ----
    int q0 = 0, q1 = 1, q2 = 2;
    float v0 = pdx, v1 = pdy, v2 = pdz;
    if (v1 > v0) { float t = v0; v0 = v1; v1 = t; int ti = q0; q0 = q1; q1 = ti; }
    if (v2 > v1) { float t = v1; v1 = v2; v2 = t; int ti = q1; q1 = q2; q2 = ti; }
    if (v1 > v0) { float t = v0; v0 = v1; v1 = t; int ti = q0; q0 = q1; q1 = ti; }
    int r0 = 0, r1 = 1, r2 = 2;
    float u0 = gdx, u1 = gdy, u2 = gdz;
    if (u1 > u0) { float t = u0; u0 = u1; u1 = t; int ti = r0; r0 = r1; r1 = ti; }
    if (u2 > u1) { float t = u1; u1 = u2; u2 = t; int ti = r1; r1 = r2; r2 = ti; }
    if (u1 > u0) { float t = u0; u0 = u1; u1 = t; int ti = r0; r0 = r1; r1 = ti; }

    float s_cdims = fabsf(v0 - u0) * frcp(u0 + 1e-8f)
                  + fabsf(v1 - u1) * frcp(u1 + 1e-8f)
                  + fabsf(v2 - u2) * frcp(u2 + 1e-8f);

    int ig0 = (r0 == 0) ? 0 : ((r1 == 0) ? 1 : 2);
    int ig1 = (r0 == 1) ? 0 : ((r1 == 1) ? 1 : 2);
    int ig2 = (r0 == 2) ? 0 : ((r1 == 2) ? 1 : 2);
    int t0 = sel3i(ig0, ig1, ig2, q0);
    int t1 = sel3i(ig0, ig1, ig2, q1);
    int t2 = sel3i(ig0, ig1, ig2, q2);

    float s_cang = 0.0f;
#pragma unroll
    for (int i = 0; i < 3; ++i) {
      float gg0 = Rg[i * 3 + 0], gg1 = Rg[i * 3 + 1], gg2 = Rg[i * 3 + 2];
      float ds = Rp[i * 3 + 0] * sel3(gg0, gg1, gg2, t0)
               + Rp[i * 3 + 1] * sel3(gg0, gg1, gg2, t1)
               + Rp[i * 3 + 2] * sel3(gg0, gg1, gg2, t2);
      float ad = fminf(fabsf(ds), 1.0f);
      s_cang += acos_fast(ad);
    }

    // ---- box bases ----
    float phx = 0.5f * pdx, phy = 0.5f * pdy, phz = 0.5f * pdz;
    float ghx = 0.5f * gdx, ghy = 0.5f * gdy, ghz = 0.5f * gdz;
    float pA0x = Rp[0] * phx, pA0y = Rp[3] * phx, pA0z = Rp[6] * phx;
    float pA1x = Rp[1] * phy, pA1y = Rp[4] * phy, pA1z = Rp[7] * phy;
    float pA2x = Rp[2] * phz, pA2y = Rp[5] * phz, pA2z = Rp[8] * phz;
    float gA0x = Rg[0] * ghx, gA0y = Rg[3] * ghx, gA0z = Rg[6] * ghx;
    float gA1x = Rg[1] * ghy, gA1y = Rg[4] * ghy, gA1z = Rg[7] * ghy;
    float gA2x = Rg[2] * ghz, gA2y = Rg[5] * ghz, gA2z = Rg[8] * ghz;

    // ---- projected IoU via closed-form OBB axis extents ----
    float pex = fabsf(pA0x) + fabsf(pA1x) + fabsf(pA2x);
    float pey = fabsf(pA0y) + fabsf(pA1y) + fabsf(pA2y);
    float pez = fabsf(pA0z) + fabsf(pA1z) + fabsf(pA2z);
    float gex = fabsf(gA0x) + fabsf(gA1x) + fabsf(gA2x);
    float gey = fabsf(gA0y) + fabsf(gA1y) + fabsf(gA2y);
    float gez = fabsf(gA0z) + fabsf(gA1z) + fabsf(gA2z);
    float pmnx = px - pex, pmxx = px + pex;
    float pmny = py - pey, pmxy = py + pey;
    float pmnz = pz - pez, pmxz = pz + pez;
    float gmnx = gx - gex, gmxx = gx + gex;
    float gmny = gy - gey, gmxy = gy + gey;
    float gmnz = gz - gez, gmxz = gz + gez;

    auto plane_iou = [&](float a1n, float a1x, float b1n, float b1x,
                         float a2n, float a2x, float b2n, float b2x,
                         float p1n, float p1x, float p2n, float p2x) -> float {
      const float eps = 1e-3f;
      float ia = fmaxf(fminf(a1x, a2x) - fmaxf(a1n, a2n) + eps, 0.0f);
      float ib = fmaxf(fminf(b1x, b2x) - fmaxf(b1n, b2n) + eps, 0.0f);
      float inter = ia * ib;
      float ar1 = (a1x - a1n + eps) * (b1x - b1n + eps);
      float ar2 = (a2x - a2n + eps) * (b2x - b2n + eps);
      float iou2d = inter * frcp(ar1 + ar2 - inter + 1e-6f);
      float hi = fmaxf(fminf(p1x, p2x) - fmaxf(p1n, p2n), 0.0f);
      float hu = (p1x - p1n) + (p2x - p2n) - hi;
      return iou2d * (hi * frcp(hu + 1e-6f));
    };
    float iou_sum = 0.0f;
    iou_sum += plane_iou(pmnx, pmxx, pmnz, pmxz, gmnx, gmxx, gmnz, gmxz,
                         pmny, pmxy, gmny, gmxy);
    iou_sum += plane_iou(pmnx, pmxx, pmny, pmxy, gmnx, gmxx, gmny, gmxy,
                         pmnz, pmxz, gmnz, gmxz);
    iou_sum += plane_iou(pmny, pmxy, pmnz, pmxz, gmny, gmxy, gmnz, gmxz,
                         pmnx, pmxx, gmnx, gmxx);
    float iou_b = fminf(fmaxf(iou_sum * (1.0f / 3.0f), 0.0f), 1.0f);

    // ---- corners (f32, constant-indexed; feed only the D matrix now) ----
    float pcx[8], pcy[8], pcz[8], gcx[8], gcy[8], gcz[8];
#pragma unroll
    for (int k = 0; k < 8; ++k) {
      float sx = (k & 4) ? -1.0f : 1.0f;
      float sy = (k & 2) ? -1.0f : 1.0f;
      float sz = (k & 1) ? -1.0f : 1.0f;
      pcx[k] = px + sx * pA0x + sy * pA1x + sz * pA2x;
      pcy[k] = py + sx * pA0y + sy * pA1y + sz * pA2y;
      pcz[k] = pz + sx * pA0z + sy * pA1z + sz * pA2z;
      gcx[k] = gx + sx * gA0x + sy * gA1x + sz * gA2x;
      gcy[k] = gy + sx * gA0y + sy * gA1y + sz * gA2y;
      gcz[k] = gz + sx * gA0z + sy * gA1z + sz * gA2z;
    }

    // ---- packed-fp16 D: D2[r][jj] = {D[r][2jj], D[r][2jj+1]} (2 j's per
    // pk-op; halves D's register footprint; r8-proven packed-gt pattern).
    // fp16 noise ~2e-3/entry -> ~2e-4 on the loss (slack 0.035). ----
    h2 GX[4], GY[4], GZ[4];
#pragma unroll
    for (int jj = 0; jj < 4; ++jj) {
      GX[jj] = h2{(_Float16)gcx[2 * jj], (_Float16)gcx[2 * jj + 1]};
      GY[jj] = h2{(_Float16)gcy[2 * jj], (_Float16)gcy[2 * jj + 1]};
      GZ[jj] = h2{(_Float16)gcz[2 * jj], (_Float16)gcz[2 * jj + 1]};
    }
    h2 D2[8][4];
#pragma unroll
    for (int r = 0; r < 8; ++r) {
      _Float16 hx = (_Float16)pcx[r];
      _Float16 hy = (_Float16)pcy[r];
      _Float16 hz = (_Float16)pcz[r];
      h2 bx = h2{hx, hx}, by = h2{hy, hy}, bz = h2{hz, hz};
#pragma unroll
      for (int jj = 0; jj < 4; ++jj)
        D2[r][jj] = __builtin_elementwise_abs(bx - GX[jj]) +
                    __builtin_elementwise_abs(by - GY[jj]) +
                    __builtin_elementwise_abs(bz - GZ[jj]);
    }

    // ---- 48-perm assignment min, packed: mask pair {m, m^1} shares one
    // h2 chain (odd-j terms half-swapped via op_sel). 24 independent
    // balanced chains -> pk_min tree. ----
    h2 gmin;
    static_for<0, 6>([&](auto P) {
      constexpr int p = decltype(P)::value;
      h2 bp;
      static_for<0, 4>([&](auto MM) {
        constexpr int mp = decltype(MM)::value;
        constexpr int m = 2 * mp;
        h2 s01 = pair_term<0, p, m>(D2) + pair_term<1, p, m>(D2);
        h2 s23 = pair_term<2, p, m>(D2) + pair_term<3, p, m>(D2);
        h2 s45 = pair_term<4, p, m>(D2) + pair_term<5, p, m>(D2);
        h2 s67 = pair_term<6, p, m>(D2) + pair_term<7, p, m>(D2);
        h2 sum = (s01 + s23) + (s45 + s67);
        if constexpr (mp == 0) bp = sum;
        else bp = __builtin_elementwise_min(bp, sum);
      });
      if constexpr (p == 0) gmin = bp;
      else gmin = __builtin_elementwise_min(gmin, bp);
    });
    float best = fminf((float)gmin[0], (float)gmin[1]);

    // ---- combine ----
    const float third = (1.0f / 3.0f);
    float loss_b = 0.15f * s_diag * third
                 + 0.2f * s_center * third
                 + 0.15f * s_quat * third
                 + 0.1f * (0.5f * s_cdims * third + 0.5f * s_cang * third)
                 + best * corner_scale
                 - 0.2f * iou_b;
    contrib = loss_b * invB;
  }

  // ---- block reduction: wave shfl -> LDS -> ONE store (no atomic) ----
  float s = contrib;
#pragma unroll
  for (int off = 32; off > 0; off >>= 1) s += __shfl_down(s, off, 64);
  __shared__ float red[BLOCK / 64];
  int lane = threadIdx.x & 63;
  int wid = threadIdx.x >> 6;
  if (lane == 0) red[wid] = s;
  __syncthreads();
  if (threadIdx.x == 0) {
    partials[blockIdx.x] = red[0] + red[1] + red[2] + red[3];
  }
}

// Stage 2: one block reduces the per-block partials; writes out directly.
__global__ __launch_bounds__(BLOCK)
void reduce_kernel(const float* __restrict__ partials, int n,
                   float* __restrict__ out) {
  float s = 0.0f;
  for (int i = threadIdx.x; i < n; i += BLOCK) s += partials[i];
#pragma unroll
  for (int off = 32; off > 0; off >>= 1) s += __shfl_down(s, off, 64);
  __shared__ float red[BLOCK / 64];
  int lane = threadIdx.x & 63;
  int wid = threadIdx.x >> 6;
  if (lane == 0) red[wid] = s;
  __syncthreads();
  if (threadIdx.x == 0) {
    out[0] = red[0] + red[1] + red[2] + red[3] + 0.2f;  // + W['iou']*1.0
  }
}

extern "C" void kernel_launch(void* const* d_in, const int* in_sizes, int n_in,
                              void* d_out, int out_size, void* d_ws, size_t ws_size,
                              hipStream_t stream) {
  const float* pred = (const float*)d_in[0];
  const float* gt = (const float*)d_in[1];
  float* out = (float*)d_out;
  float* partials = (float*)d_ws;
  int B = in_sizes[0] / 10;
  int grid = (B + BLOCK - 1) / BLOCK;
  hybrid_loss_kernel<<<grid, BLOCK, 0, stream>>>(pred, gt, partials, B,
                                                 1.0f / (float)B);
  reduce_kernel<<<1, BLOCK, 0, stream>>>(partials, grid, out);
}